// Round 9
// baseline (722.869 us; speedup 1.0000x reference)
//
#include <hip/hip_runtime.h>
#include <math.h>

#define N 16384
#define D 512
#define K 1024
#define NUM_ITERS 10
#define TEMPERATURE 0.1f
#define CONCENTRATION 0.1f
#define EPS 1e-6f

typedef unsigned short ushort_t;
typedef unsigned int uint_t;
typedef unsigned long long u64;
typedef __attribute__((ext_vector_type(4))) float floatx4;
typedef __attribute__((ext_vector_type(8))) short shortx8;

// ---------- fp16 helpers ----------
__device__ inline ushort_t f2h(float f) {
    _Float16 h = (_Float16)f;            // RNE
    return *(ushort_t*)&h;
}

__device__ inline unsigned ford(float f) {   // order-preserving float->uint
    unsigned b = __float_as_uint(f);
    return (b & 0x80000000u) ? ~b : (b | 0x80000000u);
}

__device__ inline void f4add(float4& a, const float4& b) {
    a.x += b.x; a.y += b.y; a.z += b.z; a.w += b.w;
}

__device__ inline void gld16(const void* g, void* l) {
    __builtin_amdgcn_global_load_lds(
        (const __attribute__((address_space(1))) void*)(uintptr_t)(g),
        (__attribute__((address_space(3))) void*)(uintptr_t)(l), 16, 0, 0);
}

#define WAITVM(n_lit) asm volatile("s_waitcnt vmcnt(" #n_lit ")" ::: "memory")

// ---------- split (fp32->fp16 cast, best init, centroid copy, scal zero)
// + rowsq for the K initial centroids, merged as extra blocks ----------
#define SPLIT_BLOCKS (N * D / 4 / 256)    // 8192
__global__ void split_kernel(const float* __restrict__ x, ushort_t* __restrict__ hi,
                             u64* __restrict__ best2, float* __restrict__ cent,
                             double* __restrict__ scal, float* __restrict__ csq) {
    const int bid = blockIdx.x;
    const int tid = threadIdx.x;
    if (bid < SPLIT_BLOCKS) {
        int i = bid * 256 + tid;
        float4 v = ((const float4*)x)[i];
        ushort4 hv = {f2h(v.x), f2h(v.y), f2h(v.z), f2h(v.w)};
        ((ushort4*)hi)[i] = hv;
        if (i < 2 * N) best2[i] = ~0ull;
        if (i < K * D / 4) ((float4*)cent)[i] = v;   // centroids = feats[:K]
        if (i == 0) { scal[0] = 0.0; scal[1] = 0.0; scal[2] = 0.0; *(int*)&scal[3] = 0; }
    } else {
        // rowsq for initial centroids (identical arithmetic to the old rowsq_kernel)
        int row = (bid - SPLIT_BLOCKS) * 4 + (tid >> 6);
        int lane = tid & 63;
        if (row >= K) return;
        const float* r = x + (size_t)row * D;
        float s = 0.f;
        for (int i = lane; i < D; i += 64) { float v = r[i]; s += v * v; }
        for (int off = 32; off > 0; off >>= 1) s += __shfl_down(s, off, 64);
        if (lane == 0) csq[row] = s;
    }
}

// ---------- MFMA assign v6: 256x256 tile, 8 waves, kh-granular counted-vmcnt
// pipeline + SPLIT-BARRIER phases (m201/T3 graft) ----------
// Base = round-1's assign_mfma2 (proven bit-exact): BK=64, parts per K-tile
// [A.kh0, B.kh0, A.kh1, B.kh1], stage part g+6 at phase g, vmcnt checkpoints
// every 2 phases (steady 8 = 4 parts outstanding; tail 0/4).
// NEW: each phase is split by barrier #1 between {stage issue + ds_read issue}
// and {lgkmcnt(0); MFMA}, with barrier #2 at phase end. This creates the wave
// role-split (memory-issuing waves vs MFMA-entering waves) that m196/m218b
// show is the prerequisite for counted-vmcnt + setprio to pay; with one
// barrier per phase (R1) waves stay lockstep and the CU idles at each sync.
// Race audit: stage(g+6) writes a region whose last ds_reads drained at phase
// (g-2)'s lgkmcnt(0), >= 2 barriers before the write is issued; read residency
// comes from the unchanged vmcnt checkpoints (steady: end of (u,1) retires
// through part 4u+3 covering phases (u,2),(u,3); end of (u,3) retires through
// 4u+5 covering (u+1,0),(u+1,1); prologue WAITVM(8) retires parts 0,1; tails
// vmcnt(0)@(7,1), vmcnt(4)@(6,3) re-audited). All waves run both barriers
// every phase -> no divergent barrier.
// Fragment values, lane mapping, per-frag K-order (u asc, kh0 then kh1),
// epilogue: identical to R1 -> best bit-identical -> absmax 0.0.
__global__ __launch_bounds__(512, 2) void assign_mfma6(
    const ushort_t* __restrict__ Ah, const ushort_t* __restrict__ Bh,
    const float* __restrict__ csq, u64* __restrict__ best)
{
    __shared__ __align__(16) ushort_t sA[4][8192];
    __shared__ __align__(16) ushort_t sB[4][8192];

    const int tid = threadIdx.x;
    const int lane = tid & 63;
    const int wave = tid >> 6;
    const int wr = wave >> 2, wc = wave & 3;     // 2x4 wave grid, wave tile 128x64
    const int quad = lane >> 4, l16 = lane & 15;

    // XCD-chunked swizzle: each XCD owns 8 consecutive brow x all 4 bcol.
    const int bid = (int)blockIdx.x;
    const int xid = bid & 7;
    const int s = bid >> 3;                       // 0..31
    const int brow = (xid << 3) + (s >> 2);       // 0..63
    const int bcol = s & 3;                       // 0..3
    const int row0 = brow * 256, col0 = bcol * 256;

    floatx4 acc[8][4];
#pragma unroll
    for (int a = 0; a < 8; ++a)
#pragma unroll
        for (int b = 0; b < 4; ++b) acc[a][b] = (floatx4){0.f, 0.f, 0.f, 0.f};

    // fragment-read swizzled slot offset (ushorts); independent of i/j/wr/wc
    const int swz = (quad ^ (l16 & 3) ^ ((l16 >> 2) & 3)) * 8;
    const int aoff = (wr * 128 + l16) * 32 + swz;  // + (ih*4+i)*512
    const int boff = (wc * 64 + l16) * 32 + swz;   // + j*512

    auto stage = [&](int h) {
        const int u_h = h >> 2;
        const int part = h & 3;
        const int kh = part >> 1;
        const int reg = ((u_h & 1) << 1) | kh;
        const int d_off = u_h * 64 + kh * 32;
        const ushort_t* src = (part & 1) ? Bh : Ah;
        const int r0 = (part & 1) ? col0 : row0;
        ushort_t* dstreg = ((part & 1) ? &sB[0][0] : &sA[0][0]) + reg * 8192;
#pragma unroll
        for (int ii = 0; ii < 2; ++ii) {
            const int idx = ii * 512 + tid;            // 0..1023, lane-linear per wave
            const int row = idx >> 2;
            const int kb = (idx & 3) ^ (row & 3) ^ ((row >> 2) & 3);
            gld16(src + (size_t)(r0 + row) * D + d_off + kb * 8, dstreg + idx * 8);
        }
    };

    // prologue: pre-stage parts 0..5; parts 0,1 (= tile0 kh0) retired at vmcnt(8)
    #pragma unroll
    for (int h = 0; h < 6; ++h) stage(h);
    WAITVM(8);
    __builtin_amdgcn_s_barrier();
    __builtin_amdgcn_sched_barrier(0);

    shortx8 fb[4];
#pragma unroll
    for (int u = 0; u < 8; ++u) {
        const int rbase = (u & 1) << 1;
#pragma unroll
        for (int p = 0; p < 4; ++p) {
            const int g = u * 4 + p;
            if (g + 6 < 32) stage(g + 6);          // issue prefetch (memory section)
            const int kh = p >> 1;
            const int ih = p & 1;
            const ushort_t* Areg = &sA[0][0] + (rbase + kh) * 8192;
            const ushort_t* Breg = &sB[0][0] + (rbase + kh) * 8192;
            shortx8 fa[4];
            if (ih == 0) {
#pragma unroll
                for (int j = 0; j < 4; ++j) fb[j] = *(const shortx8*)&Breg[boff + j * 512];
            }
#pragma unroll
            for (int i = 0; i < 4; ++i) fa[i] = *(const shortx8*)&Areg[aoff + (ih * 4 + i) * 512];

            __builtin_amdgcn_s_barrier();          // B1: split issue | compute
            asm volatile("s_waitcnt lgkmcnt(0)" ::: "memory");
            __builtin_amdgcn_sched_barrier(0);

            __builtin_amdgcn_s_setprio(1);
#pragma unroll
            for (int i = 0; i < 4; ++i)
#pragma unroll
                for (int j = 0; j < 4; ++j)
                    acc[ih * 4 + i][j] = __builtin_amdgcn_mfma_f32_16x16x32_f16(
                        fa[i], fb[j], acc[ih * 4 + i][j], 0, 0, 0);
            __builtin_amdgcn_s_setprio(0);

            const bool last = (u == 7 && p == 3);
            if ((p == 1 || p == 3) && !last) {     // vmcnt checkpoint every 2 phases
                if (u == 7 && p == 1)      { WAITVM(0); }
                else if (u == 6 && p == 3) { WAITVM(4); }
                else                       { WAITVM(8); }   // 4 parts in flight
            }
            if (!last) {
                __builtin_amdgcn_s_barrier();      // B2: end of phase
                __builtin_amdgcn_sched_barrier(0);
            }
        }
    }

    // epilogue: per-row argmin over this wave's 64 cols, then global atomicMin merge
    float csqv[4];
#pragma unroll
    for (int j = 0; j < 4; ++j) csqv[j] = csq[col0 + wc * 64 + j * 16 + l16];

    const int k0 = col0 + wc * 64 + l16;
#pragma unroll
    for (int i = 0; i < 8; ++i) {
#pragma unroll
        for (int r = 0; r < 4; ++r) {
            float bv = csqv[0] - 2.0f * acc[i][0][r];
            int bk = k0;
#pragma unroll
            for (int j = 1; j < 4; ++j) {
                float v = csqv[j] - 2.0f * acc[i][j][r];
                int kk = k0 + j * 16;
                if (v < bv || (v == bv && kk < bk)) { bv = v; bk = kk; }
            }
#pragma unroll
            for (int m = 1; m < 16; m <<= 1) {
                float ov = __shfl_xor(bv, m, 64);
                int ok = __shfl_xor(bk, m, 64);
                if (ov < bv || (ov == bv && ok < bk)) { bv = ov; bk = ok; }
            }
            if (l16 == 0) {
                int p = row0 + wr * 128 + i * 16 + quad * 4 + r;
                u64 pk = ((u64)ford(bv) << 32) | (unsigned)bk;
                atomicMin(&best[p], pk);
            }
        }
    }
}

// ======== round-based gather-then-process segment reduce (round-1 form) ========
#define CU_WAVES 8
#define CHUNKS (N / 128)          // 128 chunks of 128 points
#define ROUNDS 4
#define WIN (CHUNKS / ROUNDS)     // 32 chunks/round
#define CPW (WIN / CU_WAVES)      // 4 chunks per wave per round

__global__ __launch_bounds__(512) void cluster_update(
    const float* __restrict__ feats, const u64* __restrict__ best,
    u64* __restrict__ best_other,
    float* __restrict__ cent, ushort_t* __restrict__ Bh,
    float* __restrict__ csq)
{
    __shared__ int list[CU_WAVES][CPW * 128];
    __shared__ int lcnt[CU_WAVES];
    __shared__ float4 part[CU_WAVES][64][2];
    __shared__ int pcnt_s[CU_WAVES];

    const int tid = threadIdx.x;
    const int lane = tid & 63;
    const int wave = tid >> 6;
    const int k = (int)blockIdx.x;

    float4 a0 = {0.f, 0.f, 0.f, 0.f}, a1 = {0.f, 0.f, 0.f, 0.f};
    int cnttot = 0;

    for (int round = 0; round < ROUNDS; ++round) {
        int cw = 0;
#pragma unroll
        for (int cc = 0; cc < CPW; ++cc) {
            int chunk = round * WIN + wave * CPW + cc;
            ulonglong2 v = ((const ulonglong2*)best)[chunk * 64 + lane];
            int id0 = (int)(uint_t)v.x;
            int id1 = (int)(uint_t)v.y;
            int p0 = chunk * 128 + 2 * lane;
            u64 m0 = __ballot(id0 == k);
            u64 m1 = __ballot(id1 == k);
            int c0 = __popcll(m0);
            u64 lanem = (1ull << lane) - 1ull;
            if (id0 == k) list[wave][cw + __popcll(m0 & lanem)] = p0;
            if (id1 == k) list[wave][cw + c0 + __popcll(m1 & lanem)] = p0 + 1;
            cw += c0 + __popcll(m1);
        }
        if (lane == 0) lcnt[wave] = cw;
        cnttot += cw;
        __syncthreads();

        int off[CU_WAVES]; int T = 0;
#pragma unroll
        for (int j = 0; j < CU_WAVES; ++j) { off[j] = T; T += lcnt[j]; }

        for (int g0 = wave; g0 < T; g0 += CU_WAVES * 4) {
            int nb = 0; int pidx[4];
#pragma unroll
            for (int b = 0; b < 4; ++b) {
                int g = g0 + CU_WAVES * b;
                if (g < T) {
                    int j = 0;
#pragma unroll
                    for (int jj = 1; jj < CU_WAVES; ++jj) if (g >= off[jj]) j = jj;
                    pidx[nb++] = list[j][g - off[j]];
                }
            }
            float4 x[4][2];
#pragma unroll
            for (int b = 0; b < 4; ++b) if (b < nb) {
                const float4* r = (const float4*)(feats + (size_t)pidx[b] * D) + lane * 2;
                x[b][0] = r[0]; x[b][1] = r[1];
            }
#pragma unroll
            for (int b = 0; b < 4; ++b) if (b < nb) {
                f4add(a0, x[b][0]); f4add(a1, x[b][1]);
            }
        }
        __syncthreads();
    }

    part[wave][lane][0] = a0; part[wave][lane][1] = a1;
    if (lane == 0) pcnt_s[wave] = cnttot;
    __syncthreads();

    if (wave == 0) {
        float4 s0 = part[0][lane][0], s1 = part[0][lane][1];
        int c = pcnt_s[0];
#pragma unroll
        for (int w = 1; w < CU_WAVES; ++w) {
            f4add(s0, part[w][lane][0]); f4add(s1, part[w][lane][1]);
            c += pcnt_s[w];
        }

        float4* crow = (float4*)(cent + (size_t)k * D) + lane * 2;
        float4 c0, c1;
        if (c > 0) {
            float cf = (float)c;
            c0 = (float4){s0.x / cf, s0.y / cf, s0.z / cf, s0.w / cf};
            c1 = (float4){s1.x / cf, s1.y / cf, s1.z / cf, s1.w / cf};
        } else {
            c0 = crow[0]; c1 = crow[1];
        }
        crow[0] = c0; crow[1] = c1;

        ushort4 hv;
        hv.x = f2h(c0.x); hv.y = f2h(c0.y); hv.z = f2h(c0.z); hv.w = f2h(c0.w);
        ((ushort4*)(Bh + (size_t)k * D))[lane * 2] = hv;
        hv.x = f2h(c1.x); hv.y = f2h(c1.y); hv.z = f2h(c1.z); hv.w = f2h(c1.w);
        ((ushort4*)(Bh + (size_t)k * D))[lane * 2 + 1] = hv;

        float s = c0.x * c0.x + c0.y * c0.y + c0.z * c0.z + c0.w * c0.w
                + c1.x * c1.x + c1.y * c1.y + c1.z * c1.z + c1.w * c1.w;
        for (int o = 32; o > 0; o >>= 1) s += __shfl_xor(s, o, 64);
        if (lane == 0) csq[k] = s;
    }

    // reset our 16-entry slice of the OTHER buffer for the next assign
    if (tid < 16) best_other[k * 16 + tid] = ~0ull;
}

// ---------- residual^2 segment sum, same scan scheme (round-1 form) ----------
__global__ __launch_bounds__(512) void dist_gather(
    const float* __restrict__ feats, const float* __restrict__ cent,
    const u64* __restrict__ best, float* __restrict__ dists)
{
    __shared__ int list[CU_WAVES][CPW * 128];
    __shared__ int lcnt[CU_WAVES];
    __shared__ float4 part[CU_WAVES][64][2];

    const int tid = threadIdx.x;
    const int lane = tid & 63;
    const int wave = tid >> 6;
    const int k = (int)blockIdx.x;

    const float4* crow = (const float4*)(cent + (size_t)k * D) + lane * 2;
    const float4 c0 = crow[0], c1 = crow[1];

    float4 a0 = {0.f, 0.f, 0.f, 0.f}, a1 = {0.f, 0.f, 0.f, 0.f};

    for (int round = 0; round < ROUNDS; ++round) {
        int cw = 0;
#pragma unroll
        for (int cc = 0; cc < CPW; ++cc) {
            int chunk = round * WIN + wave * CPW + cc;
            ulonglong2 v = ((const ulonglong2*)best)[chunk * 64 + lane];
            int id0 = (int)(uint_t)v.x;
            int id1 = (int)(uint_t)v.y;
            int p0 = chunk * 128 + 2 * lane;
            u64 m0 = __ballot(id0 == k);
            u64 m1 = __ballot(id1 == k);
            int cc0 = __popcll(m0);
            u64 lanem = (1ull << lane) - 1ull;
            if (id0 == k) list[wave][cw + __popcll(m0 & lanem)] = p0;
            if (id1 == k) list[wave][cw + cc0 + __popcll(m1 & lanem)] = p0 + 1;
            cw += cc0 + __popcll(m1);
        }
        if (lane == 0) lcnt[wave] = cw;
        __syncthreads();

        int off[CU_WAVES]; int T = 0;
#pragma unroll
        for (int j = 0; j < CU_WAVES; ++j) { off[j] = T; T += lcnt[j]; }

        for (int g0 = wave; g0 < T; g0 += CU_WAVES * 4) {
            int nb = 0; int pidx[4];
#pragma unroll
            for (int b = 0; b < 4; ++b) {
                int g = g0 + CU_WAVES * b;
                if (g < T) {
                    int j = 0;
#pragma unroll
                    for (int jj = 1; jj < CU_WAVES; ++jj) if (g >= off[jj]) j = jj;
                    pidx[nb++] = list[j][g - off[j]];
                }
            }
            float4 x[4][2];
#pragma unroll
            for (int b = 0; b < 4; ++b) if (b < nb) {
                const float4* r = (const float4*)(feats + (size_t)pidx[b] * D) + lane * 2;
                x[b][0] = r[0]; x[b][1] = r[1];
            }
#pragma unroll
            for (int b = 0; b < 4; ++b) if (b < nb) {
                float r;
                r = x[b][0].x - c0.x; a0.x += r * r;  r = x[b][0].y - c0.y; a0.y += r * r;
                r = x[b][0].z - c0.z; a0.z += r * r;  r = x[b][0].w - c0.w; a0.w += r * r;
                r = x[b][1].x - c1.x; a1.x += r * r;  r = x[b][1].y - c1.y; a1.y += r * r;
                r = x[b][1].z - c1.z; a1.z += r * r;  r = x[b][1].w - c1.w; a1.w += r * r;
            }
        }
        __syncthreads();
    }

    part[wave][lane][0] = a0; part[wave][lane][1] = a1;
    __syncthreads();
    if (wave == 0) {
        float4 s0 = part[0][lane][0], s1 = part[0][lane][1];
#pragma unroll
        for (int w = 1; w < CU_WAVES; ++w) { f4add(s0, part[w][lane][0]); f4add(s1, part[w][lane][1]); }
        float4* drow = (float4*)(dists + (size_t)k * D) + lane * 2;
        drow[0] = s0; drow[1] = s1;
    }
}

// ---------- fused loss: S-pass, resident-grid ticket barrier, e/nl-pass, finalize ----
__global__ void loss_fused(const float* __restrict__ dists, double* __restrict__ scal,
                           float* __restrict__ out) {
    const int tid = threadIdx.x;
    int* cnt = (int*)&scal[3];
    __shared__ float red[4];
    __shared__ double Sbc;

    // pass 1: S = sum exp(-d/CONC)
    float v = 0.f;
    for (int idx = blockIdx.x * 256 + tid; idx < K * D; idx += 256 * 256)
        v += expf(-(dists[idx] / CONCENTRATION));
    for (int off = 32; off > 0; off >>= 1) v += __shfl_down(v, off, 64);
    if ((tid & 63) == 0) red[tid >> 6] = v;
    __syncthreads();
    if (tid == 0) {
        atomicAdd(&scal[0], (double)(red[0] + red[1] + red[2] + red[3]));
        __threadfence();
        atomicAdd(cnt, 1);
        while (atomicAdd(cnt, 0) < 256) __builtin_amdgcn_s_sleep(1);
        Sbc = atomicAdd(&scal[0], 0.0);     // coherent read of completed S
    }
    __syncthreads();
    const float S = (float)Sbc;

    // pass 2: entropy + nll partials
    float e = 0.f, nl = 0.f;
    for (int idx = blockIdx.x * 256 + tid; idx < K * D; idx += 256 * 256) {
        float dv = dists[idx];
        float p = expf(-(dv / CONCENTRATION));
        float qq = p / S;
        e += qq * logf(qq + EPS);
        float p2 = expf(-(dv / TEMPERATURE));
        nl += logf(p2 + EPS);
    }
    __shared__ float rede[4];
    __shared__ float redn[4];
    for (int off = 32; off > 0; off >>= 1) { e += __shfl_down(e, off, 64); nl += __shfl_down(nl, off, 64); }
    if ((tid & 63) == 0) { rede[tid >> 6] = e; redn[tid >> 6] = nl; }
    __syncthreads();
    if (tid == 0) {
        atomicAdd(&scal[1], (double)(rede[0] + rede[1] + rede[2] + rede[3]));
        atomicAdd(&scal[2], (double)(redn[0] + redn[1] + redn[2] + redn[3]));
        __threadfence();
        int t = atomicAdd(cnt, 1);          // tickets 256..511
        if (t == 511) {                     // last block finalizes
            double e_s = atomicAdd(&scal[1], 0.0);
            double n_s = atomicAdd(&scal[2], 0.0);
            double kd = (double)(K * D);
            double entropy = e_s / kd;
            double nll = -(n_s / kd);
            out[0] = (float)(entropy + nll);
        }
    }
}

extern "C" void kernel_launch(void* const* d_in, const int* in_sizes, int n_in,
                              void* d_out, int out_size, void* d_ws, size_t ws_size,
                              hipStream_t stream) {
    const float* feats = (const float*)d_in[0];
    float* out = (float*)d_out;

    ushort_t* Ah = (ushort_t*)d_ws;                  // N*D
    ushort_t* Bh = Ah + (size_t)N * D;               // K*D
    float* centroids = (float*)(Bh + (size_t)K * D); // K*D
    float* dists     = centroids + (size_t)K * D;    // K*D
    float* csq       = dists + (size_t)K * D;        // K
    u64*   best0     = (u64*)(csq + K);              // N  (contiguous with best1)
    u64*   best1     = best0 + N;                    // N
    double* scal     = (double*)(best1 + N);         // 4 (S, e, nl, counter)

    split_kernel<<<SPLIT_BLOCKS + K / 4, 256, 0, stream>>>(feats, Ah, best0, centroids,
                                                           scal, csq);

    for (int it = 0; it < NUM_ITERS; ++it) {
        u64* cur = (it & 1) ? best1 : best0;
        u64* oth = (it & 1) ? best0 : best1;
        const ushort_t* bh = (it == 0) ? Ah : Bh;   // iter0: init centroids = feats[:K]
        assign_mfma6<<<(N / 256) * (K / 256), 512, 0, stream>>>(Ah, bh, csq, cur);
        cluster_update<<<K, 512, 0, stream>>>(feats, cur, oth, centroids, Bh, csq);
    }
    u64* fin = (NUM_ITERS & 1) ? best1 : best0;   // reset by last cluster_update
    assign_mfma6<<<(N / 256) * (K / 256), 512, 0, stream>>>(Ah, Bh, csq, fin);

    dist_gather<<<K, 512, 0, stream>>>(feats, centroids, fin, dists);

    loss_fused<<<256, 256, 0, stream>>>(dists, scal, out);
}

// Round 10
// 671.489 us; speedup vs baseline: 1.0765x; 1.0765x over previous
//
#include <hip/hip_runtime.h>
#include <math.h>

#define N 16384
#define D 512
#define K 1024
#define NUM_ITERS 10
#define TEMPERATURE 0.1f
#define CONCENTRATION 0.1f
#define EPS 1e-6f

typedef unsigned short ushort_t;
typedef unsigned int uint_t;
typedef unsigned long long u64;
typedef __attribute__((ext_vector_type(4))) float floatx4;
typedef __attribute__((ext_vector_type(8))) short shortx8;

// ---------- fp16 helpers ----------
__device__ inline ushort_t f2h(float f) {
    _Float16 h = (_Float16)f;            // RNE
    return *(ushort_t*)&h;
}

__device__ inline unsigned ford(float f) {   // order-preserving float->uint
    unsigned b = __float_as_uint(f);
    return (b & 0x80000000u) ? ~b : (b | 0x80000000u);
}

__device__ inline void f4add(float4& a, const float4& b) {
    a.x += b.x; a.y += b.y; a.z += b.z; a.w += b.w;
}

__device__ inline void gld16(const void* g, void* l) {
    __builtin_amdgcn_global_load_lds(
        (const __attribute__((address_space(1))) void*)(uintptr_t)(g),
        (__attribute__((address_space(3))) void*)(uintptr_t)(l), 16, 0, 0);
}

#define WAITVM(n_lit) asm volatile("s_waitcnt vmcnt(" #n_lit ")" ::: "memory")

// ---------- split (fp32->fp16 cast, best init, centroid copy, scal zero)
// + rowsq for the K initial centroids, merged as extra blocks ----------
#define SPLIT_BLOCKS (N * D / 4 / 256)    // 8192
__global__ void split_kernel(const float* __restrict__ x, ushort_t* __restrict__ hi,
                             u64* __restrict__ best2, float* __restrict__ cent,
                             double* __restrict__ scal, float* __restrict__ csq) {
    const int bid = blockIdx.x;
    const int tid = threadIdx.x;
    if (bid < SPLIT_BLOCKS) {
        int i = bid * 256 + tid;
        float4 v = ((const float4*)x)[i];
        ushort4 hv = {f2h(v.x), f2h(v.y), f2h(v.z), f2h(v.w)};
        ((ushort4*)hi)[i] = hv;
        if (i < 2 * N) best2[i] = ~0ull;
        if (i < K * D / 4) ((float4*)cent)[i] = v;   // centroids = feats[:K]
        if (i == 0) { scal[0] = 0.0; scal[1] = 0.0; scal[2] = 0.0; *(int*)&scal[3] = 0; }
    } else {
        // rowsq for initial centroids (identical arithmetic to the old rowsq_kernel)
        int row = (bid - SPLIT_BLOCKS) * 4 + (tid >> 6);
        int lane = tid & 63;
        if (row >= K) return;
        const float* r = x + (size_t)row * D;
        float s = 0.f;
        for (int i = lane; i < D; i += 64) { float v = r[i]; s += v * v; }
        for (int off = 32; off > 0; off >>= 1) s += __shfl_down(s, off, 64);
        if (lane == 0) csq[row] = s;
    }
}

// ---------- MFMA assign v3 (RESTORED BEST, R6 = 675 us): 256x128 tile, BK=32,
// 8 waves (4x2), triple-buffer ring LDS 72 KB -> 2 blocks/CU ----------
// Exploration record: v2 256²/1blk (703), v4 A-in-reg (826), v5 ring-4 (682,
// null), v6 split-barrier (723). Occupancy 1->2 blocks/CU was the only real
// lever (-28 us); prefetch depth and barrier micro-structure are null/negative.
// v3 sits at the 128-VGPR/2-block register cliff; K=512 (16 BK=32 tiles) gives
// no room for deeper phase pipelines (m201-style needs K-depth).
// Pipeline: stage K-tile t+2 at top of tile t (3 gld16/thread); per-tile
// barrier waits vmcnt(3) (newest stage in flight) -> ~2 tile-intervals cover.
// K-order per output fragment: t=0..15 ascending == all prior versions ->
// bit-identical accumulation; argmin windows/tie-break/atomicMin unchanged.
__global__ __launch_bounds__(512, 4) void assign_mfma3(
    const ushort_t* __restrict__ Ah, const ushort_t* __restrict__ Bh,
    const float* __restrict__ csq, u64* __restrict__ best)
{
    __shared__ __align__(16) ushort_t sA[3 * 8192];   // 3 regions x 256 rows x 32 halfs
    __shared__ __align__(16) ushort_t sB[3 * 4096];   // 3 regions x 128 rows x 32 halfs

    const int tid = threadIdx.x;
    const int lane = tid & 63;
    const int wave = tid >> 6;
    const int wr = wave >> 1, wc = wave & 1;      // 4x2 wave grid, wave tile 64x64
    const int quad = lane >> 4, l16 = lane & 15;

    // XCD-chunked swizzle: XCD x owns brows 8x..8x+7, all 8 bcols
    // (A panel 2 MB + whole B 1 MB fits the 4 MB per-XCD L2).
    const int bid = (int)blockIdx.x;
    const int xid = bid & 7;
    const int s = bid >> 3;                       // 0..63
    const int brow = (xid << 3) + (s >> 3);       // 0..63
    const int bcol = s & 7;                       // 0..7
    const int row0 = brow * 256, col0 = bcol * 128;

    floatx4 acc[4][4];
#pragma unroll
    for (int a = 0; a < 4; ++a)
#pragma unroll
        for (int b = 0; b < 4; ++b) acc[a][b] = (floatx4){0.f, 0.f, 0.f, 0.f};

    // fragment-read swizzled slot offset (halfs); independent of i/j/wr/wc
    const int swz = (quad ^ (l16 & 3) ^ ((l16 >> 2) & 3)) * 8;
    const int aoff = (wr * 64 + l16) * 32 + swz;   // + i*512  (i = 16-row frag)
    const int boff = (wc * 64 + l16) * 32 + swz;   // + j*512

    auto stage = [&](int t2) {                     // 3 gld16 per thread
        const int r = t2 % 3;
        ushort_t* dA = sA + r * 8192;
        ushort_t* dB = sB + r * 4096;
        const int d0 = t2 * 32;
#pragma unroll
        for (int ii = 0; ii < 2; ++ii) {
            const int idx = ii * 512 + tid;        // 0..1023, lane-linear per wave
            const int row = idx >> 2;
            const int kb = (idx & 3) ^ (row & 3) ^ ((row >> 2) & 3);
            gld16(Ah + (size_t)(row0 + row) * D + d0 + kb * 8, dA + idx * 8);
        }
        {
            const int idx = tid;                   // 0..511 -> 128 rows x 4 slots
            const int row = idx >> 2;
            const int kb = (idx & 3) ^ (row & 3) ^ ((row >> 2) & 3);
            gld16(Bh + (size_t)(col0 + row) * D + d0 + kb * 8, dB + idx * 8);
        }
    };

    // prologue: stage tiles 0,1; wait tile0 complete (allow tile1's 3 in flight)
    stage(0); stage(1);
    WAITVM(3);
    __builtin_amdgcn_s_barrier();
    __builtin_amdgcn_sched_barrier(0);

#pragma unroll
    for (int t = 0; t < 16; ++t) {
        if (t + 2 < 16) stage(t + 2);              // prefetch 2 tiles ahead
        const ushort_t* Ar = sA + (t % 3) * 8192;
        const ushort_t* Br = sB + (t % 3) * 4096;
        shortx8 fa[4], fb[4];
#pragma unroll
        for (int j = 0; j < 4; ++j) fb[j] = *(const shortx8*)&Br[boff + j * 512];
#pragma unroll
        for (int i = 0; i < 4; ++i) fa[i] = *(const shortx8*)&Ar[aoff + i * 512];
        __builtin_amdgcn_s_setprio(1);
#pragma unroll
        for (int i = 0; i < 4; ++i)
#pragma unroll
            for (int j = 0; j < 4; ++j)
                acc[i][j] = __builtin_amdgcn_mfma_f32_16x16x32_f16(
                    fa[i], fb[j], acc[i][j], 0, 0, 0);
        __builtin_amdgcn_s_setprio(0);
        if (t < 15) {
            asm volatile("s_waitcnt lgkmcnt(0)" ::: "memory");  // region reads done
            if (t < 14) { WAITVM(3); } else { WAITVM(0); }      // next tile resident
            __builtin_amdgcn_s_barrier();
            __builtin_amdgcn_sched_barrier(0);
        }
    }

    // epilogue: per-row argmin over this wave's 64 cols, then global atomicMin merge
    float csqv[4];
#pragma unroll
    for (int j = 0; j < 4; ++j) csqv[j] = csq[col0 + wc * 64 + j * 16 + l16];

    const int k0 = col0 + wc * 64 + l16;
#pragma unroll
    for (int i = 0; i < 4; ++i) {
#pragma unroll
        for (int r = 0; r < 4; ++r) {
            float bv = csqv[0] - 2.0f * acc[i][0][r];
            int bk = k0;
#pragma unroll
            for (int j = 1; j < 4; ++j) {
                float v = csqv[j] - 2.0f * acc[i][j][r];
                int kk = k0 + j * 16;
                if (v < bv || (v == bv && kk < bk)) { bv = v; bk = kk; }
            }
#pragma unroll
            for (int m = 1; m < 16; m <<= 1) {
                float ov = __shfl_xor(bv, m, 64);
                int ok = __shfl_xor(bk, m, 64);
                if (ov < bv || (ov == bv && ok < bk)) { bv = ov; bk = ok; }
            }
            if (l16 == 0) {
                int p = row0 + wr * 64 + i * 16 + quad * 4 + r;
                u64 pk = ((u64)ford(bv) << 32) | (unsigned)bk;
                atomicMin(&best[p], pk);
            }
        }
    }
}

// ======== round-based gather-then-process segment reduce (round-1 form) ========
#define CU_WAVES 8
#define CHUNKS (N / 128)          // 128 chunks of 128 points
#define ROUNDS 4
#define WIN (CHUNKS / ROUNDS)     // 32 chunks/round
#define CPW (WIN / CU_WAVES)      // 4 chunks per wave per round

__global__ __launch_bounds__(512) void cluster_update(
    const float* __restrict__ feats, const u64* __restrict__ best,
    u64* __restrict__ best_other,
    float* __restrict__ cent, ushort_t* __restrict__ Bh,
    float* __restrict__ csq)
{
    __shared__ int list[CU_WAVES][CPW * 128];
    __shared__ int lcnt[CU_WAVES];
    __shared__ float4 part[CU_WAVES][64][2];
    __shared__ int pcnt_s[CU_WAVES];

    const int tid = threadIdx.x;
    const int lane = tid & 63;
    const int wave = tid >> 6;
    const int k = (int)blockIdx.x;

    float4 a0 = {0.f, 0.f, 0.f, 0.f}, a1 = {0.f, 0.f, 0.f, 0.f};
    int cnttot = 0;

    for (int round = 0; round < ROUNDS; ++round) {
        int cw = 0;
#pragma unroll
        for (int cc = 0; cc < CPW; ++cc) {
            int chunk = round * WIN + wave * CPW + cc;
            ulonglong2 v = ((const ulonglong2*)best)[chunk * 64 + lane];
            int id0 = (int)(uint_t)v.x;
            int id1 = (int)(uint_t)v.y;
            int p0 = chunk * 128 + 2 * lane;
            u64 m0 = __ballot(id0 == k);
            u64 m1 = __ballot(id1 == k);
            int c0 = __popcll(m0);
            u64 lanem = (1ull << lane) - 1ull;
            if (id0 == k) list[wave][cw + __popcll(m0 & lanem)] = p0;
            if (id1 == k) list[wave][cw + c0 + __popcll(m1 & lanem)] = p0 + 1;
            cw += c0 + __popcll(m1);
        }
        if (lane == 0) lcnt[wave] = cw;
        cnttot += cw;
        __syncthreads();

        int off[CU_WAVES]; int T = 0;
#pragma unroll
        for (int j = 0; j < CU_WAVES; ++j) { off[j] = T; T += lcnt[j]; }

        for (int g0 = wave; g0 < T; g0 += CU_WAVES * 4) {
            int nb = 0; int pidx[4];
#pragma unroll
            for (int b = 0; b < 4; ++b) {
                int g = g0 + CU_WAVES * b;
                if (g < T) {
                    int j = 0;
#pragma unroll
                    for (int jj = 1; jj < CU_WAVES; ++jj) if (g >= off[jj]) j = jj;
                    pidx[nb++] = list[j][g - off[j]];
                }
            }
            float4 x[4][2];
#pragma unroll
            for (int b = 0; b < 4; ++b) if (b < nb) {
                const float4* r = (const float4*)(feats + (size_t)pidx[b] * D) + lane * 2;
                x[b][0] = r[0]; x[b][1] = r[1];
            }
#pragma unroll
            for (int b = 0; b < 4; ++b) if (b < nb) {
                f4add(a0, x[b][0]); f4add(a1, x[b][1]);
            }
        }
        __syncthreads();
    }

    part[wave][lane][0] = a0; part[wave][lane][1] = a1;
    if (lane == 0) pcnt_s[wave] = cnttot;
    __syncthreads();

    if (wave == 0) {
        float4 s0 = part[0][lane][0], s1 = part[0][lane][1];
        int c = pcnt_s[0];
#pragma unroll
        for (int w = 1; w < CU_WAVES; ++w) {
            f4add(s0, part[w][lane][0]); f4add(s1, part[w][lane][1]);
            c += pcnt_s[w];
        }

        float4* crow = (float4*)(cent + (size_t)k * D) + lane * 2;
        float4 c0, c1;
        if (c > 0) {
            float cf = (float)c;
            c0 = (float4){s0.x / cf, s0.y / cf, s0.z / cf, s0.w / cf};
            c1 = (float4){s1.x / cf, s1.y / cf, s1.z / cf, s1.w / cf};
        } else {
            c0 = crow[0]; c1 = crow[1];
        }
        crow[0] = c0; crow[1] = c1;

        ushort4 hv;
        hv.x = f2h(c0.x); hv.y = f2h(c0.y); hv.z = f2h(c0.z); hv.w = f2h(c0.w);
        ((ushort4*)(Bh + (size_t)k * D))[lane * 2] = hv;
        hv.x = f2h(c1.x); hv.y = f2h(c1.y); hv.z = f2h(c1.z); hv.w = f2h(c1.w);
        ((ushort4*)(Bh + (size_t)k * D))[lane * 2 + 1] = hv;

        float s = c0.x * c0.x + c0.y * c0.y + c0.z * c0.z + c0.w * c0.w
                + c1.x * c1.x + c1.y * c1.y + c1.z * c1.z + c1.w * c1.w;
        for (int o = 32; o > 0; o >>= 1) s += __shfl_xor(s, o, 64);
        if (lane == 0) csq[k] = s;
    }

    // reset our 16-entry slice of the OTHER buffer for the next assign
    if (tid < 16) best_other[k * 16 + tid] = ~0ull;
}

// ---------- residual^2 segment sum, same scan scheme (round-1 form) ----------
__global__ __launch_bounds__(512) void dist_gather(
    const float* __restrict__ feats, const float* __restrict__ cent,
    const u64* __restrict__ best, float* __restrict__ dists)
{
    __shared__ int list[CU_WAVES][CPW * 128];
    __shared__ int lcnt[CU_WAVES];
    __shared__ float4 part[CU_WAVES][64][2];

    const int tid = threadIdx.x;
    const int lane = tid & 63;
    const int wave = tid >> 6;
    const int k = (int)blockIdx.x;

    const float4* crow = (const float4*)(cent + (size_t)k * D) + lane * 2;
    const float4 c0 = crow[0], c1 = crow[1];

    float4 a0 = {0.f, 0.f, 0.f, 0.f}, a1 = {0.f, 0.f, 0.f, 0.f};

    for (int round = 0; round < ROUNDS; ++round) {
        int cw = 0;
#pragma unroll
        for (int cc = 0; cc < CPW; ++cc) {
            int chunk = round * WIN + wave * CPW + cc;
            ulonglong2 v = ((const ulonglong2*)best)[chunk * 64 + lane];
            int id0 = (int)(uint_t)v.x;
            int id1 = (int)(uint_t)v.y;
            int p0 = chunk * 128 + 2 * lane;
            u64 m0 = __ballot(id0 == k);
            u64 m1 = __ballot(id1 == k);
            int cc0 = __popcll(m0);
            u64 lanem = (1ull << lane) - 1ull;
            if (id0 == k) list[wave][cw + __popcll(m0 & lanem)] = p0;
            if (id1 == k) list[wave][cw + cc0 + __popcll(m1 & lanem)] = p0 + 1;
            cw += cc0 + __popcll(m1);
        }
        if (lane == 0) lcnt[wave] = cw;
        __syncthreads();

        int off[CU_WAVES]; int T = 0;
#pragma unroll
        for (int j = 0; j < CU_WAVES; ++j) { off[j] = T; T += lcnt[j]; }

        for (int g0 = wave; g0 < T; g0 += CU_WAVES * 4) {
            int nb = 0; int pidx[4];
#pragma unroll
            for (int b = 0; b < 4; ++b) {
                int g = g0 + CU_WAVES * b;
                if (g < T) {
                    int j = 0;
#pragma unroll
                    for (int jj = 1; jj < CU_WAVES; ++jj) if (g >= off[jj]) j = jj;
                    pidx[nb++] = list[j][g - off[j]];
                }
            }
            float4 x[4][2];
#pragma unroll
            for (int b = 0; b < 4; ++b) if (b < nb) {
                const float4* r = (const float4*)(feats + (size_t)pidx[b] * D) + lane * 2;
                x[b][0] = r[0]; x[b][1] = r[1];
            }
#pragma unroll
            for (int b = 0; b < 4; ++b) if (b < nb) {
                float r;
                r = x[b][0].x - c0.x; a0.x += r * r;  r = x[b][0].y - c0.y; a0.y += r * r;
                r = x[b][0].z - c0.z; a0.z += r * r;  r = x[b][0].w - c0.w; a0.w += r * r;
                r = x[b][1].x - c1.x; a1.x += r * r;  r = x[b][1].y - c1.y; a1.y += r * r;
                r = x[b][1].z - c1.z; a1.z += r * r;  r = x[b][1].w - c1.w; a1.w += r * r;
            }
        }
        __syncthreads();
    }

    part[wave][lane][0] = a0; part[wave][lane][1] = a1;
    __syncthreads();
    if (wave == 0) {
        float4 s0 = part[0][lane][0], s1 = part[0][lane][1];
#pragma unroll
        for (int w = 1; w < CU_WAVES; ++w) { f4add(s0, part[w][lane][0]); f4add(s1, part[w][lane][1]); }
        float4* drow = (float4*)(dists + (size_t)k * D) + lane * 2;
        drow[0] = s0; drow[1] = s1;
    }
}

// ---------- fused loss: S-pass, resident-grid ticket barrier, e/nl-pass, finalize ----
__global__ void loss_fused(const float* __restrict__ dists, double* __restrict__ scal,
                           float* __restrict__ out) {
    const int tid = threadIdx.x;
    int* cnt = (int*)&scal[3];
    __shared__ float red[4];
    __shared__ double Sbc;

    // pass 1: S = sum exp(-d/CONC)
    float v = 0.f;
    for (int idx = blockIdx.x * 256 + tid; idx < K * D; idx += 256 * 256)
        v += expf(-(dists[idx] / CONCENTRATION));
    for (int off = 32; off > 0; off >>= 1) v += __shfl_down(v, off, 64);
    if ((tid & 63) == 0) red[tid >> 6] = v;
    __syncthreads();
    if (tid == 0) {
        atomicAdd(&scal[0], (double)(red[0] + red[1] + red[2] + red[3]));
        __threadfence();
        atomicAdd(cnt, 1);
        while (atomicAdd(cnt, 0) < 256) __builtin_amdgcn_s_sleep(1);
        Sbc = atomicAdd(&scal[0], 0.0);     // coherent read of completed S
    }
    __syncthreads();
    const float S = (float)Sbc;

    // pass 2: entropy + nll partials
    float e = 0.f, nl = 0.f;
    for (int idx = blockIdx.x * 256 + tid; idx < K * D; idx += 256 * 256) {
        float dv = dists[idx];
        float p = expf(-(dv / CONCENTRATION));
        float qq = p / S;
        e += qq * logf(qq + EPS);
        float p2 = expf(-(dv / TEMPERATURE));
        nl += logf(p2 + EPS);
    }
    __shared__ float rede[4];
    __shared__ float redn[4];
    for (int off = 32; off > 0; off >>= 1) { e += __shfl_down(e, off, 64); nl += __shfl_down(nl, off, 64); }
    if ((tid & 63) == 0) { rede[tid >> 6] = e; redn[tid >> 6] = nl; }
    __syncthreads();
    if (tid == 0) {
        atomicAdd(&scal[1], (double)(rede[0] + rede[1] + rede[2] + rede[3]));
        atomicAdd(&scal[2], (double)(redn[0] + redn[1] + redn[2] + redn[3]));
        __threadfence();
        int t = atomicAdd(cnt, 1);          // tickets 256..511
        if (t == 511) {                     // last block finalizes
            double e_s = atomicAdd(&scal[1], 0.0);
            double n_s = atomicAdd(&scal[2], 0.0);
            double kd = (double)(K * D);
            double entropy = e_s / kd;
            double nll = -(n_s / kd);
            out[0] = (float)(entropy + nll);
        }
    }
}

extern "C" void kernel_launch(void* const* d_in, const int* in_sizes, int n_in,
                              void* d_out, int out_size, void* d_ws, size_t ws_size,
                              hipStream_t stream) {
    const float* feats = (const float*)d_in[0];
    float* out = (float*)d_out;

    ushort_t* Ah = (ushort_t*)d_ws;                  // N*D
    ushort_t* Bh = Ah + (size_t)N * D;               // K*D
    float* centroids = (float*)(Bh + (size_t)K * D); // K*D
    float* dists     = centroids + (size_t)K * D;    // K*D
    float* csq       = dists + (size_t)K * D;        // K
    u64*   best0     = (u64*)(csq + K);              // N  (contiguous with best1)
    u64*   best1     = best0 + N;                    // N
    double* scal     = (double*)(best1 + N);         // 4 (S, e, nl, counter)

    split_kernel<<<SPLIT_BLOCKS + K / 4, 256, 0, stream>>>(feats, Ah, best0, centroids,
                                                           scal, csq);

    for (int it = 0; it < NUM_ITERS; ++it) {
        u64* cur = (it & 1) ? best1 : best0;
        u64* oth = (it & 1) ? best0 : best1;
        const ushort_t* bh = (it == 0) ? Ah : Bh;   // iter0: init centroids = feats[:K]
        assign_mfma3<<<(N / 256) * (K / 128), 512, 0, stream>>>(Ah, bh, csq, cur);
        cluster_update<<<K, 512, 0, stream>>>(feats, cur, oth, centroids, Bh, csq);
    }
    u64* fin = (NUM_ITERS & 1) ? best1 : best0;   // reset by last cluster_update
    assign_mfma3<<<(N / 256) * (K / 128), 512, 0, stream>>>(Ah, Bh, csq, fin);

    dist_gather<<<K, 512, 0, stream>>>(feats, centroids, fin, dists);

    loss_fused<<<256, 256, 0, stream>>>(dists, scal, out);
}